// Round 8
// baseline (1391.446 us; speedup 1.0000x reference)
//
#include <hip/hip_runtime.h>
#include <hip/hip_bf16.h>
#include <hip/hip_fp8.h>

typedef __attribute__((ext_vector_type(4))) float f32x4;

#define AS1 __attribute__((address_space(1)))
#define AS3 __attribute__((address_space(3)))

static constexpr int Mdim = 4096;
static constexpr int Kdim = 7168;
static constexpr int Ndim = 16384;
static constexpr int KB   = Kdim / 128;   // 56 scale blocks
static constexpr float FP8_MAX = 448.0f;

// compiler-fence + raw barrier (no implicit vmcnt(0) drain)
#define BARRIER() do { asm volatile("" ::: "memory"); \
                       __builtin_amdgcn_s_barrier();  \
                       asm volatile("" ::: "memory"); } while (0)

#define MFMA_FP8 __builtin_amdgcn_mfma_f32_16x16x32_fp8_fp8

// ---------------------------------------------------------------------------
// Kernel 1: activation quant  x[M,K] f32 -> xq[M,K] fp8  +  xs_t[KB][M] f32
// per (1x128) block: s = amax/448; xq = fp8_rne(x/s); xs_t[kb][row] = s
// ---------------------------------------------------------------------------
__global__ __launch_bounds__(256) void quant_x_kernel(
    const float* __restrict__ x, unsigned char* __restrict__ xq,
    float* __restrict__ xst)
{
    constexpr int NBLK = Mdim * KB;
    const int lane = threadIdx.x & 63;
    const int wid  = (blockIdx.x * 256 + threadIdx.x) >> 6;
    const int nw   = (gridDim.x * 256) >> 6;

    for (int b = wid; b < NBLK; b += nw) {
        size_t base = (size_t)b * 128 + lane * 2;
        float2 v = *reinterpret_cast<const float2*>(x + base);
        float amax = fmaxf(fabsf(v.x), fabsf(v.y));
#pragma unroll
        for (int off = 32; off > 0; off >>= 1)
            amax = fmaxf(amax, __shfl_xor(amax, off));
        float s = amax * (1.0f / FP8_MAX);
        unsigned char q0 = 0, q1 = 0;
        if (s > 0.0f) {
            q0 = __hip_fp8_e4m3(v.x / s).__x;
            q1 = __hip_fp8_e4m3(v.y / s).__x;
        }
        *reinterpret_cast<unsigned short*>(xq + base) =
            (unsigned short)(q0 | ((unsigned short)q1 << 8));
        if (lane == 0) {
            int row = b / KB, kb = b - row * KB;
            xst[(size_t)kb * Mdim + row] = s;
        }
    }
}

// ---------------------------------------------------------------------------
// Kernel 2: weight quant  w[N,K] f32 -> w8[N,K] fp8 (plain RNE cast; ws is
// applied inside the GEMM now)
// ---------------------------------------------------------------------------
__global__ __launch_bounds__(256) void quant_w_kernel(
    const float* __restrict__ w, unsigned char* __restrict__ w8)
{
    constexpr size_t NCHUNK = (size_t)Ndim * Kdim / 8;

    size_t idx    = (size_t)blockIdx.x * 256 + threadIdx.x;
    size_t stride = (size_t)gridDim.x * 256;

    for (size_t c = idx; c < NCHUNK; c += stride) {
        const float* src = w + c * 8;
        float4 v0 = *reinterpret_cast<const float4*>(src);
        float4 v1 = *reinterpret_cast<const float4*>(src + 4);
        unsigned int lo = (unsigned int)__hip_fp8_e4m3(v0.x).__x
                        | ((unsigned int)__hip_fp8_e4m3(v0.y).__x << 8)
                        | ((unsigned int)__hip_fp8_e4m3(v0.z).__x << 16)
                        | ((unsigned int)__hip_fp8_e4m3(v0.w).__x << 24);
        unsigned int hi = (unsigned int)__hip_fp8_e4m3(v1.x).__x
                        | ((unsigned int)__hip_fp8_e4m3(v1.y).__x << 8)
                        | ((unsigned int)__hip_fp8_e4m3(v1.z).__x << 16)
                        | ((unsigned int)__hip_fp8_e4m3(v1.w).__x << 24);
        uint2 p; p.x = lo; p.y = hi;
        *reinterpret_cast<uint2*>(w8 + c * 8) = p;
    }
}

// ---------------------------------------------------------------------------
// Kernel 3: 256x256 NT GEMM, fp8-resident, 16x16x32 fp8 MFMA, per-tile
// f32 scale merge.  C[M,N] f32 = sum_kb xs[m,kb]*ws[nb,kb]*(xq[m,:]·w8[n,:])
//
// Schedule = round-7 verified 2-window protocol, constants rescaled for fp8:
//   LDS 64 KiB = 2 buf x { A0,A1,B0,B1 } regions of [128 rows][64 B fp8];
//   stage stream j (j&3: 0:B0 1:B1 2:A0 3:A1 of tile j>>2, buffer (j>>2)&1),
//   ONE global_load_lds (16B) per thread per stage call (region 8 KB).
//   Boundary wait vmcnt(2) (1 load per call; 2 newest calls in flight),
//   drain vmcnt(0) for last two tiles.  W1 reads a0,b0,b1; W2 reads a1;
//   W1 stages A@buf^1, W2 stages B@buf(t+2) — disjointness as round 7.
//
// Swizzle for 64-B rows: phys_slot = logical_slot ^ ((row>>1)&3) (16B slots).
//   Quarter-wave check: lanes lr 0..15 read (row=base+lr, fixed col): slot
//   groups {2s,2s+1,2s+8,2s+9} pair opposite row-parities -> opposite bank
//   halves -> 2-way = free. Applied on ds_read addr AND global stage source.
//
// Fragment (fp8 16x16x32, i64): lane l: row = l&15, k = (l>>4)*8 + byte.
// Per (m,n) pair: pacc = mfma(ks0); pacc = mfma(ks1); acc += sv[m]*pacc
// where sv[m] = xs_t[kb][row(m,j)] * ws[nb][kb]  (f32x4, j=0..3).
// ---------------------------------------------------------------------------
constexpr int BM = 256, BN = 256, BK = 64;
constexpr int NT  = Kdim / BK;            // 112 K-tiles
constexpr int NBN = Ndim / BN;            // 64
constexpr int NWG = (Mdim / BM) * NBN;    // 1024 (%8 == 0)
constexpr int K1  = Kdim;                 // fp8 row stride in bytes

__global__ __launch_bounds__(512, 2) void gemm256_fp8_kernel(
    const unsigned char* __restrict__ Ag,   // xq  [M][K] fp8
    const unsigned char* __restrict__ Bg,   // w8  [N][K] fp8
    const float* __restrict__ xsT,          // [KB][M] f32
    const float* __restrict__ Wsc,          // [N/128][KB] f32
    float* __restrict__ C)
{
    extern __shared__ char smem[];   // 65536 bytes

    const int tid  = threadIdx.x;
    const int w    = tid >> 6;
    const int lane = tid & 63;
    const int wr   = w >> 2;          // 0..1
    const int wc   = w & 3;           // 0..3
    const int lr   = lane & 15;
    const int lk   = lane >> 4;

    // XCD-bijective block swizzle
    int bid = (int)blockIdx.x;
    int swz = (bid & 7) * (NWG >> 3) + (bid >> 3);
    const int bm = (swz / NBN) * BM;
    const int bn = (swz % NBN) * BN;

    // swizzled ds_read byte offsets within a 64-B row
    const int sw   = ((lr >> 1) & 3) << 4;
    const int col0 = (lk * 8) ^ sw;          // ks = 0
    const int col1 = (32 + lk * 8) ^ sw;     // ks = 1
    const int bRow = (wc & 1) * 64;          // wave's row base in its B region

    // scale bases
    const int nb  = (bn + wc * 64) >> 7;                  // wave-uniform
    const int rsb = bm + wr * 128 + lk * 4;               // scale row base

    // staging: 1 chunk (16B) per thread per call
    const int rowS = tid >> 2;                            // 0..127
    const int colS = (((tid & 3) ^ ((rowS >> 1) & 3))) * 16;  // swizzled col
    const size_t offG = (size_t)rowS * K1 + colS;
    const int ldsW = tid * 16;

    const char* Ab = (const char*)Ag + (size_t)bm * K1;
    const char* Bb = (const char*)Bg + (size_t)bn * K1;

    auto stage = [&](int j) {
        if (j >= 4 * NT) return;
        const int T    = j >> 2;
        const int r    = j & 3;          // 0:B0 1:B1 2:A0 3:A1
        const int isA  = r >> 1;
        const int half = r & 1;
        const int regByte = (T & 1) * 32768 + (isA ? 0 : 16384) + half * 8192;
        const char* g = (isA ? Ab : Bb) + (size_t)half * (128 * (size_t)K1)
                        + (size_t)T * 64 + offG;
        __builtin_amdgcn_global_load_lds((const AS1 void*)g,
                                         (AS3 void*)(smem + regByte + ldsW),
                                         16, 0, 0);
    };

    // ---- prologue: tile0 (all 4 halves) + tile1 (B0,B1) ----
    for (int j = 0; j < 6; ++j) stage(j);
    asm volatile("s_waitcnt vmcnt(2)" ::: "memory");   // j<=3: tile0 resident
    BARRIER();

    f32x4 acc[8][4] = {};

    for (int t = 0; t < NT; ++t) {
        const int buf = t & 1;
        const int kb  = t >> 1;
        const char* aB = smem + buf * 32768 + wr * 8192;
        const char* bB = smem + buf * 32768 + 16384 + (wc >> 1) * 8192;
        long long a0[4][2], a1[4][2], b0[2][2], b1[2][2];
        f32x4 sv[4];

        const float wsv = Wsc[nb * KB + kb];
        const float* xrow = xsT + (size_t)kb * Mdim + rsb;

        // ================= W1 : Q0 + Q1 =================
        stage(4 * t + 6);
#pragma unroll
        for (int m = 0; m < 4; ++m) {
            const char* p = aB + (m * 16 + lr) * 64;
            a0[m][0] = *(const long long*)(p + col0);
            a0[m][1] = *(const long long*)(p + col1);
        }
#pragma unroll
        for (int n = 0; n < 2; ++n) {
            const char* p = bB + (bRow + n * 16 + lr) * 64;
            b0[n][0] = *(const long long*)(p + col0);
            b0[n][1] = *(const long long*)(p + col1);
        }
#pragma unroll
        for (int m = 0; m < 4; ++m) {
            f32x4 s = *reinterpret_cast<const f32x4*>(xrow + m * 16);
            sv[m] = s * wsv;
        }
        __builtin_amdgcn_s_setprio(1);
#pragma unroll
        for (int m = 0; m < 4; ++m)
#pragma unroll
            for (int n = 0; n < 2; ++n) {
                f32x4 pacc = {0.f, 0.f, 0.f, 0.f};
                pacc = MFMA_FP8(a0[m][0], b0[n][0], pacc, 0, 0, 0);
                pacc = MFMA_FP8(a0[m][1], b0[n][1], pacc, 0, 0, 0);
                acc[m][n] += sv[m] * pacc;
            }
        __builtin_amdgcn_s_setprio(0);

        stage(4 * t + 7);
#pragma unroll
        for (int n = 0; n < 2; ++n) {
            const char* p = bB + (bRow + (n + 2) * 16 + lr) * 64;
            b1[n][0] = *(const long long*)(p + col0);
            b1[n][1] = *(const long long*)(p + col1);
        }
        __builtin_amdgcn_s_setprio(1);
#pragma unroll
        for (int m = 0; m < 4; ++m)
#pragma unroll
            for (int n = 0; n < 2; ++n) {
                f32x4 pacc = {0.f, 0.f, 0.f, 0.f};
                pacc = MFMA_FP8(a0[m][0], b1[n][0], pacc, 0, 0, 0);
                pacc = MFMA_FP8(a0[m][1], b1[n][1], pacc, 0, 0, 0);
                acc[m][n + 2] += sv[m] * pacc;
            }
        __builtin_amdgcn_s_setprio(0);
        BARRIER();   // W1 -> W2

        // ================= W2 : Q2 + Q3 =================
        stage(4 * t + 8);
#pragma unroll
        for (int m = 0; m < 4; ++m) {
            const char* p = aB + ((m + 4) * 16 + lr) * 64;
            a1[m][0] = *(const long long*)(p + col0);
            a1[m][1] = *(const long long*)(p + col1);
        }
#pragma unroll
        for (int m = 0; m < 4; ++m) {
            f32x4 s = *reinterpret_cast<const f32x4*>(xrow + 64 + m * 16);
            sv[m] = s * wsv;
        }
        __builtin_amdgcn_s_setprio(1);
#pragma unroll
        for (int m = 0; m < 4; ++m)
#pragma unroll
            for (int n = 0; n < 2; ++n) {
                f32x4 pacc = {0.f, 0.f, 0.f, 0.f};
                pacc = MFMA_FP8(a1[m][0], b0[n][0], pacc, 0, 0, 0);
                pacc = MFMA_FP8(a1[m][1], b0[n][1], pacc, 0, 0, 0);
                acc[m + 4][n] += sv[m] * pacc;
            }
        __builtin_amdgcn_s_setprio(0);

        stage(4 * t + 9);
        __builtin_amdgcn_s_setprio(1);
#pragma unroll
        for (int m = 0; m < 4; ++m)
#pragma unroll
            for (int n = 0; n < 2; ++n) {
                f32x4 pacc = {0.f, 0.f, 0.f, 0.f};
                pacc = MFMA_FP8(a1[m][0], b1[n][0], pacc, 0, 0, 0);
                pacc = MFMA_FP8(a1[m][1], b1[n][1], pacc, 0, 0, 0);
                acc[m + 4][n + 2] += sv[m] * pacc;
            }
        __builtin_amdgcn_s_setprio(0);
        if (t < NT - 2) { asm volatile("s_waitcnt vmcnt(2)" ::: "memory"); }
        else            { asm volatile("s_waitcnt vmcnt(0)" ::: "memory"); }
        BARRIER();   // tile boundary: tile t+1 fully resident
    }

    // ---- epilogue: C/D layout col = lr, row = lk*4 + j ----
#pragma unroll
    for (int m = 0; m < 8; ++m) {
#pragma unroll
        for (int n = 0; n < 4; ++n) {
            const int row0 = bm + wr * 128 + m * 16 + lk * 4;
            const int col  = bn + wc * 64 + n * 16 + lr;
#pragma unroll
            for (int j = 0; j < 4; ++j)
                C[(size_t)(row0 + j) * Ndim + col] = acc[m][n][j];
        }
    }
}

// ---------------------------------------------------------------------------
extern "C" void kernel_launch(void* const* d_in, const int* in_sizes, int n_in,
                              void* d_out, int out_size, void* d_ws, size_t ws_size,
                              hipStream_t stream) {
    const float* x  = (const float*)d_in[0];
    const float* w  = (const float*)d_in[1];
    const float* ws = (const float*)d_in[2];

    unsigned char* xq  = (unsigned char*)d_ws;                       // 29.4 MB
    unsigned char* w8  = xq + (size_t)Mdim * Kdim;                   // 117.4 MB
    float*         xst = (float*)(w8 + (size_t)Ndim * Kdim);         // 0.92 MB

    quant_x_kernel<<<2048, 256, 0, stream>>>(x, xq, xst);
    quant_w_kernel<<<4096, 256, 0, stream>>>(w, w8);

    hipFuncSetAttribute((const void*)gemm256_fp8_kernel,
                        hipFuncAttributeMaxDynamicSharedMemorySize, 65536);
    gemm256_fp8_kernel<<<NWG, 512, 65536, stream>>>(xq, w8, xst, ws,
                                                    (float*)d_out);
}

// Round 9
// 1352.180 us; speedup vs baseline: 1.0290x; 1.0290x over previous
//
#include <hip/hip_runtime.h>
#include <hip/hip_bf16.h>
#include <hip/hip_fp8.h>

typedef __attribute__((ext_vector_type(4))) float f32x4;
typedef __attribute__((ext_vector_type(2))) long long ll2;

#define AS1 __attribute__((address_space(1)))
#define AS3 __attribute__((address_space(3)))

static constexpr int Mdim = 4096;
static constexpr int Kdim = 7168;
static constexpr int Ndim = 16384;
static constexpr int KB   = Kdim / 128;   // 56 scale blocks
static constexpr float FP8_MAX = 448.0f;

// compiler-fence + raw barrier (no implicit vmcnt(0) drain)
#define BARRIER() do { asm volatile("" ::: "memory"); \
                       __builtin_amdgcn_s_barrier();  \
                       asm volatile("" ::: "memory"); } while (0)

#define MFMA_FP8 __builtin_amdgcn_mfma_f32_16x16x32_fp8_fp8

// ---------------------------------------------------------------------------
// Kernel 1: activation quant  x[M,K] f32 -> xq[M,K] fp8  +  xs_t[KB][M] f32
// ---------------------------------------------------------------------------
__global__ __launch_bounds__(256) void quant_x_kernel(
    const float* __restrict__ x, unsigned char* __restrict__ xq,
    float* __restrict__ xst)
{
    constexpr int NBLK = Mdim * KB;
    const int lane = threadIdx.x & 63;
    const int wid  = (blockIdx.x * 256 + threadIdx.x) >> 6;
    const int nw   = (gridDim.x * 256) >> 6;

    for (int b = wid; b < NBLK; b += nw) {
        size_t base = (size_t)b * 128 + lane * 2;
        float2 v = *reinterpret_cast<const float2*>(x + base);
        float amax = fmaxf(fabsf(v.x), fabsf(v.y));
#pragma unroll
        for (int off = 32; off > 0; off >>= 1)
            amax = fmaxf(amax, __shfl_xor(amax, off));
        float s = amax * (1.0f / FP8_MAX);
        unsigned char q0 = 0, q1 = 0;
        if (s > 0.0f) {
            q0 = __hip_fp8_e4m3(v.x / s).__x;
            q1 = __hip_fp8_e4m3(v.y / s).__x;
        }
        *reinterpret_cast<unsigned short*>(xq + base) =
            (unsigned short)(q0 | ((unsigned short)q1 << 8));
        if (lane == 0) {
            int row = b / KB, kb = b - row * KB;
            xst[(size_t)kb * Mdim + row] = s;
        }
    }
}

// ---------------------------------------------------------------------------
// Kernel 2: weight quant  w[N,K] f32 -> w8[N,K] fp8 (plain RNE cast)
// ---------------------------------------------------------------------------
__global__ __launch_bounds__(256) void quant_w_kernel(
    const float* __restrict__ w, unsigned char* __restrict__ w8)
{
    constexpr size_t NCHUNK = (size_t)Ndim * Kdim / 8;

    size_t idx    = (size_t)blockIdx.x * 256 + threadIdx.x;
    size_t stride = (size_t)gridDim.x * 256;

    for (size_t c = idx; c < NCHUNK; c += stride) {
        const float* src = w + c * 8;
        float4 v0 = *reinterpret_cast<const float4*>(src);
        float4 v1 = *reinterpret_cast<const float4*>(src + 4);
        unsigned int lo = (unsigned int)__hip_fp8_e4m3(v0.x).__x
                        | ((unsigned int)__hip_fp8_e4m3(v0.y).__x << 8)
                        | ((unsigned int)__hip_fp8_e4m3(v0.z).__x << 16)
                        | ((unsigned int)__hip_fp8_e4m3(v0.w).__x << 24);
        unsigned int hi = (unsigned int)__hip_fp8_e4m3(v1.x).__x
                        | ((unsigned int)__hip_fp8_e4m3(v1.y).__x << 8)
                        | ((unsigned int)__hip_fp8_e4m3(v1.z).__x << 16)
                        | ((unsigned int)__hip_fp8_e4m3(v1.w).__x << 24);
        uint2 p; p.x = lo; p.y = hi;
        *reinterpret_cast<uint2*>(w8 + c * 8) = p;
    }
}

// ---------------------------------------------------------------------------
// Kernel 3: 256x256 NT GEMM, fp8-resident, b128 fragment reads with
// k-permutation.  C = sum_kb xs[m,kb]*ws[nb,kb]*(xq·w8)
//
// Round-8 schedule/protocol (passed correctness) with ONE change: fragment
// reads are ds_read_b128 (16 B), not b64.
//
// k-permutation: lane (lk = lane>>4) reads logical col 16*lk of its row =
// k-bytes [16lk, 16lk+16). MFMA call 0 consumes the lo 8 B, call 1 the hi
// 8 B. Calls sum disjoint k-subsets whose union is all 64 k-bytes; A and B
// use the same permutation, so the dot product is exact.
//
// Bank analysis (b128 -> 8-lane conflict groups, 128 B/cy):
//   rows base+lr, base%16==0; phys slot = lk ^ ((lr>>1)&3); row parity
//   (lr&1) selects bank half (64-B rows). Lanes lr=0..7: 4 slots x 2
//   halves = 32 banks exactly once -> conflict-free (round-3 class).
// Staging swizzle unchanged (16-B granular, same involution both sides).
//
// LDS 64 KiB = 2 buf x { A0,A1,B0,B1 } regions of [128 rows][64 B fp8];
// stage stream j (j&3: 0:B0 1:B1 2:A0 3:A1, buffer (j>>2)&1), 1 load (16B)
// per thread per call; boundary vmcnt(2), drain vmcnt(0) last two tiles.
// W1 reads a0,b0,b1 / stages A@buf^1; W2 reads a1 / stages B@(t+2).
// Scale merge per tile: acc[m][n] += sv[m] * pacc  (sv = xs rows * ws).
// ---------------------------------------------------------------------------
constexpr int BM = 256, BN = 256, BK = 64;
constexpr int NT  = Kdim / BK;            // 112 K-tiles
constexpr int NBN = Ndim / BN;            // 64
constexpr int NWG = (Mdim / BM) * NBN;    // 1024 (%8 == 0)
constexpr int K1  = Kdim;                 // fp8 row stride in bytes

__global__ __launch_bounds__(512, 2) void gemm256_fp8_kernel(
    const unsigned char* __restrict__ Ag,   // xq  [M][K] fp8
    const unsigned char* __restrict__ Bg,   // w8  [N][K] fp8
    const float* __restrict__ xsT,          // [KB][M] f32
    const float* __restrict__ Wsc,          // [N/128][KB] f32
    float* __restrict__ C)
{
    extern __shared__ char smem[];   // 65536 bytes

    const int tid  = threadIdx.x;
    const int w    = tid >> 6;
    const int lane = tid & 63;
    const int wr   = w >> 2;          // 0..1
    const int wc   = w & 3;           // 0..3
    const int lr   = lane & 15;
    const int lk   = lane >> 4;

    // XCD-bijective block swizzle
    int bid = (int)blockIdx.x;
    int swz = (bid & 7) * (NWG >> 3) + (bid >> 3);
    const int bm = (swz / NBN) * BM;
    const int bn = (swz % NBN) * BN;

    // swizzled b128 read column (bytes within a 64-B row); lane-constant:
    // phys slot = lk ^ ((lr>>1)&3)  (row bases are multiples of 16)
    const int colF = (lk ^ ((lr >> 1) & 3)) << 4;
    const int bRow = (wc & 1) * 64;   // wave's row base in its B region

    // scale bases
    const int nb  = (bn + wc * 64) >> 7;                  // wave-uniform
    const int rsb = bm + wr * 128 + lk * 4;               // scale row base

    // staging: 1 chunk (16B) per thread per call (same involution as read)
    const int rowS = tid >> 2;                            // 0..127
    const int colS = (((tid & 3) ^ ((rowS >> 1) & 3))) * 16;  // swizzled col
    const size_t offG = (size_t)rowS * K1 + colS;
    const int ldsW = tid * 16;

    const char* Ab = (const char*)Ag + (size_t)bm * K1;
    const char* Bb = (const char*)Bg + (size_t)bn * K1;

    auto stage = [&](int j) {
        if (j >= 4 * NT) return;
        const int T    = j >> 2;
        const int r    = j & 3;          // 0:B0 1:B1 2:A0 3:A1
        const int isA  = r >> 1;
        const int half = r & 1;
        const int regByte = (T & 1) * 32768 + (isA ? 0 : 16384) + half * 8192;
        const char* g = (isA ? Ab : Bb) + (size_t)half * (128 * (size_t)K1)
                        + (size_t)T * 64 + offG;
        __builtin_amdgcn_global_load_lds((const AS1 void*)g,
                                         (AS3 void*)(smem + regByte + ldsW),
                                         16, 0, 0);
    };

    // ---- prologue: tile0 (all 4 halves) + tile1 (B0,B1) ----
    for (int j = 0; j < 6; ++j) stage(j);
    asm volatile("s_waitcnt vmcnt(2)" ::: "memory");   // j<=3: tile0 resident
    BARRIER();

    f32x4 acc[8][4] = {};

    for (int t = 0; t < NT; ++t) {
        const int buf = t & 1;
        const int kb  = t >> 1;
        const char* aB = smem + buf * 32768 + wr * 8192;
        const char* bB = smem + buf * 32768 + 16384 + (wc >> 1) * 8192;
        ll2 a0[4], a1[4], b0[2], b1[2];
        f32x4 sv[4];

        const float wsv = Wsc[nb * KB + kb];
        const float* xrow = xsT + (size_t)kb * Mdim + rsb;

        // ================= W1 : Q0 + Q1 =================
        stage(4 * t + 6);
#pragma unroll
        for (int m = 0; m < 4; ++m)
            a0[m] = *(const ll2*)(aB + (m * 16 + lr) * 64 + colF);
#pragma unroll
        for (int n = 0; n < 2; ++n)
            b0[n] = *(const ll2*)(bB + (bRow + n * 16 + lr) * 64 + colF);
#pragma unroll
        for (int m = 0; m < 4; ++m) {
            f32x4 s = *reinterpret_cast<const f32x4*>(xrow + m * 16);
            sv[m] = s * wsv;
        }
        __builtin_amdgcn_s_setprio(1);
#pragma unroll
        for (int m = 0; m < 4; ++m)
#pragma unroll
            for (int n = 0; n < 2; ++n) {
                f32x4 pacc = {0.f, 0.f, 0.f, 0.f};
                pacc = MFMA_FP8(a0[m][0], b0[n][0], pacc, 0, 0, 0);
                pacc = MFMA_FP8(a0[m][1], b0[n][1], pacc, 0, 0, 0);
                acc[m][n] += sv[m] * pacc;
            }
        __builtin_amdgcn_s_setprio(0);

        stage(4 * t + 7);
#pragma unroll
        for (int n = 0; n < 2; ++n)
            b1[n] = *(const ll2*)(bB + (bRow + (n + 2) * 16 + lr) * 64 + colF);
        __builtin_amdgcn_s_setprio(1);
#pragma unroll
        for (int m = 0; m < 4; ++m)
#pragma unroll
            for (int n = 0; n < 2; ++n) {
                f32x4 pacc = {0.f, 0.f, 0.f, 0.f};
                pacc = MFMA_FP8(a0[m][0], b1[n][0], pacc, 0, 0, 0);
                pacc = MFMA_FP8(a0[m][1], b1[n][1], pacc, 0, 0, 0);
                acc[m][n + 2] += sv[m] * pacc;
            }
        __builtin_amdgcn_s_setprio(0);
        BARRIER();   // W1 -> W2

        // ================= W2 : Q2 + Q3 =================
        stage(4 * t + 8);
#pragma unroll
        for (int m = 0; m < 4; ++m)
            a1[m] = *(const ll2*)(aB + ((m + 4) * 16 + lr) * 64 + colF);
#pragma unroll
        for (int m = 0; m < 4; ++m) {
            f32x4 s = *reinterpret_cast<const f32x4*>(xrow + 64 + m * 16);
            sv[m] = s * wsv;
        }
        __builtin_amdgcn_s_setprio(1);
#pragma unroll
        for (int m = 0; m < 4; ++m)
#pragma unroll
            for (int n = 0; n < 2; ++n) {
                f32x4 pacc = {0.f, 0.f, 0.f, 0.f};
                pacc = MFMA_FP8(a1[m][0], b0[n][0], pacc, 0, 0, 0);
                pacc = MFMA_FP8(a1[m][1], b0[n][1], pacc, 0, 0, 0);
                acc[m + 4][n] += sv[m] * pacc;
            }
        __builtin_amdgcn_s_setprio(0);

        stage(4 * t + 9);
        __builtin_amdgcn_s_setprio(1);
#pragma unroll
        for (int m = 0; m < 4; ++m)
#pragma unroll
            for (int n = 0; n < 2; ++n) {
                f32x4 pacc = {0.f, 0.f, 0.f, 0.f};
                pacc = MFMA_FP8(a1[m][0], b1[n][0], pacc, 0, 0, 0);
                pacc = MFMA_FP8(a1[m][1], b1[n][1], pacc, 0, 0, 0);
                acc[m + 4][n + 2] += sv[m] * pacc;
            }
        __builtin_amdgcn_s_setprio(0);
        if (t < NT - 2) { asm volatile("s_waitcnt vmcnt(2)" ::: "memory"); }
        else            { asm volatile("s_waitcnt vmcnt(0)" ::: "memory"); }
        BARRIER();   // tile boundary: tile t+1 fully resident
    }

    // ---- epilogue: C/D layout col = lr, row = lk*4 + j ----
#pragma unroll
    for (int m = 0; m < 8; ++m) {
#pragma unroll
        for (int n = 0; n < 4; ++n) {
            const int row0 = bm + wr * 128 + m * 16 + lk * 4;
            const int col  = bn + wc * 64 + n * 16 + lr;
#pragma unroll
            for (int j = 0; j < 4; ++j)
                C[(size_t)(row0 + j) * Ndim + col] = acc[m][n][j];
        }
    }
}

// ---------------------------------------------------------------------------
extern "C" void kernel_launch(void* const* d_in, const int* in_sizes, int n_in,
                              void* d_out, int out_size, void* d_ws, size_t ws_size,
                              hipStream_t stream) {
    const float* x  = (const float*)d_in[0];
    const float* w  = (const float*)d_in[1];
    const float* ws = (const float*)d_in[2];

    unsigned char* xq  = (unsigned char*)d_ws;                       // 29.4 MB
    unsigned char* w8  = xq + (size_t)Mdim * Kdim;                   // 117.4 MB
    float*         xst = (float*)(w8 + (size_t)Ndim * Kdim);         // 0.92 MB

    quant_x_kernel<<<2048, 256, 0, stream>>>(x, xq, xst);
    quant_w_kernel<<<4096, 256, 0, stream>>>(w, w8);

    hipFuncSetAttribute((const void*)gemm256_fp8_kernel,
                        hipFuncAttributeMaxDynamicSharedMemorySize, 65536);
    gemm256_fp8_kernel<<<NWG, 512, 65536, stream>>>(xq, w8, xst, ws,
                                                    (float*)d_out);
}

// Round 10
// 1043.665 us; speedup vs baseline: 1.3332x; 1.2956x over previous
//
#include <hip/hip_runtime.h>
#include <hip/hip_bf16.h>
#include <hip/hip_fp8.h>

typedef __attribute__((ext_vector_type(4))) float f32x4;
typedef __attribute__((ext_vector_type(2))) long long ll2;

#define AS1 __attribute__((address_space(1)))
#define AS3 __attribute__((address_space(3)))

static constexpr int Mdim = 4096;
static constexpr int Kdim = 7168;
static constexpr int Ndim = 16384;
static constexpr int KB   = Kdim / 128;   // 56 scale blocks
static constexpr float FP8_MAX = 448.0f;

// compiler-fence + raw barrier (no implicit vmcnt(0) drain)
#define BARRIER() do { asm volatile("" ::: "memory"); \
                       __builtin_amdgcn_s_barrier();  \
                       asm volatile("" ::: "memory"); } while (0)

#define MFMA_FP8 __builtin_amdgcn_mfma_f32_16x16x32_fp8_fp8

// ---------------------------------------------------------------------------
// Kernel 1: activation quant  x[M,K] f32 -> xq[M,K] fp8  +  xs_t[KB][M] f32
// ---------------------------------------------------------------------------
__global__ __launch_bounds__(256) void quant_x_kernel(
    const float* __restrict__ x, unsigned char* __restrict__ xq,
    float* __restrict__ xst)
{
    constexpr int NBLK = Mdim * KB;
    const int lane = threadIdx.x & 63;
    const int wid  = (blockIdx.x * 256 + threadIdx.x) >> 6;
    const int nw   = (gridDim.x * 256) >> 6;

    for (int b = wid; b < NBLK; b += nw) {
        size_t base = (size_t)b * 128 + lane * 2;
        float2 v = *reinterpret_cast<const float2*>(x + base);
        float amax = fmaxf(fabsf(v.x), fabsf(v.y));
#pragma unroll
        for (int off = 32; off > 0; off >>= 1)
            amax = fmaxf(amax, __shfl_xor(amax, off));
        float s = amax * (1.0f / FP8_MAX);
        unsigned char q0 = 0, q1 = 0;
        if (s > 0.0f) {
            q0 = __hip_fp8_e4m3(v.x / s).__x;
            q1 = __hip_fp8_e4m3(v.y / s).__x;
        }
        *reinterpret_cast<unsigned short*>(xq + base) =
            (unsigned short)(q0 | ((unsigned short)q1 << 8));
        if (lane == 0) {
            int row = b / KB, kb = b - row * KB;
            xst[(size_t)kb * Mdim + row] = s;
        }
    }
}

// ---------------------------------------------------------------------------
// Kernel 2: weight quant  w[N,K] f32 -> w8[N,K] fp8 (plain RNE cast)
// ---------------------------------------------------------------------------
__global__ __launch_bounds__(256) void quant_w_kernel(
    const float* __restrict__ w, unsigned char* __restrict__ w8)
{
    constexpr size_t NCHUNK = (size_t)Ndim * Kdim / 8;

    size_t idx    = (size_t)blockIdx.x * 256 + threadIdx.x;
    size_t stride = (size_t)gridDim.x * 256;

    for (size_t c = idx; c < NCHUNK; c += stride) {
        const float* src = w + c * 8;
        float4 v0 = *reinterpret_cast<const float4*>(src);
        float4 v1 = *reinterpret_cast<const float4*>(src + 4);
        unsigned int lo = (unsigned int)__hip_fp8_e4m3(v0.x).__x
                        | ((unsigned int)__hip_fp8_e4m3(v0.y).__x << 8)
                        | ((unsigned int)__hip_fp8_e4m3(v0.z).__x << 16)
                        | ((unsigned int)__hip_fp8_e4m3(v0.w).__x << 24);
        unsigned int hi = (unsigned int)__hip_fp8_e4m3(v1.x).__x
                        | ((unsigned int)__hip_fp8_e4m3(v1.y).__x << 8)
                        | ((unsigned int)__hip_fp8_e4m3(v1.z).__x << 16)
                        | ((unsigned int)__hip_fp8_e4m3(v1.w).__x << 24);
        uint2 p; p.x = lo; p.y = hi;
        *reinterpret_cast<uint2*>(w8 + c * 8) = p;
    }
}

// ---------------------------------------------------------------------------
// Kernel 3: 256x256 NT GEMM, fp8-resident, b128 reads (round-9 verified),
// scales served from a persistent LDS region (NO VMEM in the K-loop except
// the 4 stage calls -> the counted-vmcnt protocol is exact again).
//
// LDS map (123328 B):
//   [0,65536):      2 buf x { A0@0, A1@8192, B0@16384, B1@24576 } of
//                   [128 rows][64 B fp8]
//   [65536,122880): xs slice  [56 kb][256 rows] f32  (rows bm..bm+256)
//   [122880,123328): ws slice [2 nb-blocks][56 kb] f32
//
// k-permutation b128 reads (round 9, conflict-free): lane reads 16 B at
// phys slot lk ^ ((lr>>1)&3); MFMA call 0 takes lo 8 B, call 1 hi 8 B —
// same permutation on A and B => exact dot product.
//
// Stage stream j (j&3: 0:B0 1:B1 2:A0 3:A1, buffer (j>>2)&1), 1 load/thread
// per call; boundary vmcnt(2), drain vmcnt(0) last two tiles.
// W1 reads a0,b0,b1 / stages A@buf^1; W2 reads a1 / stages B@(t+2).
// Prologue FIFO: 7 xs chunks (+1 ws chunk, wave0) then 6 stage calls;
// vmcnt(2) leaves only the 2 newest stage calls outstanding -> scales and
// tile0 resident before the first barrier.
// Scale merge per tile: acc[m][n] += sv[m] * pacc, sv from LDS broadcast.
// ---------------------------------------------------------------------------
constexpr int BM = 256, BN = 256, BK = 64;
constexpr int NT  = Kdim / BK;            // 112 K-tiles
constexpr int NBN = Ndim / BN;            // 64
constexpr int NWG = (Mdim / BM) * NBN;    // 1024 (%8 == 0)
constexpr int K1  = Kdim;                 // fp8 row stride in bytes
constexpr int XS_OFF = 65536;             // xs LDS offset
constexpr int WS_OFF = XS_OFF + 56 * 1024;       // 122880
constexpr int LDS_TOT = WS_OFF + 448;            // 123328

__global__ __launch_bounds__(512, 2) void gemm256_fp8_kernel(
    const unsigned char* __restrict__ Ag,   // xq  [M][K] fp8
    const unsigned char* __restrict__ Bg,   // w8  [N][K] fp8
    const float* __restrict__ xsT,          // [KB][M] f32
    const float* __restrict__ Wsc,          // [N/128][KB] f32
    float* __restrict__ C)
{
    extern __shared__ char smem[];   // LDS_TOT bytes

    const int tid  = threadIdx.x;
    const int w    = tid >> 6;
    const int lane = tid & 63;
    const int wr   = w >> 2;          // 0..1
    const int wc   = w & 3;           // 0..3
    const int lr   = lane & 15;
    const int lk   = lane >> 4;

    // XCD-bijective block swizzle
    int bid = (int)blockIdx.x;
    int swz = (bid & 7) * (NWG >> 3) + (bid >> 3);
    const int bm = (swz / NBN) * BM;
    const int bn = (swz % NBN) * BN;

    // swizzled b128 read column (bytes within a 64-B row)
    const int colF = (lk ^ ((lr >> 1) & 3)) << 4;
    const int bRow = (wc & 1) * 64;   // wave's row base in its B region

    // LDS scale bases (all reads broadcast within 16-lane groups)
    const char* xsL0 = smem + XS_OFF + (wr * 128 + lk * 4) * 4;
    const char* wsL  = smem + WS_OFF + (wc >> 1) * (KB * 4);

    // staging: 1 chunk (16B) per thread per call (involution matches read)
    const int rowS = tid >> 2;                            // 0..127
    const int colS = (((tid & 3) ^ ((rowS >> 1) & 3))) * 16;  // swizzled col
    const size_t offG = (size_t)rowS * K1 + colS;
    const int ldsW = tid * 16;

    const char* Ab = (const char*)Ag + (size_t)bm * K1;
    const char* Bb = (const char*)Bg + (size_t)bn * K1;

    auto stage = [&](int j) {
        if (j >= 4 * NT) return;
        const int T    = j >> 2;
        const int r    = j & 3;          // 0:B0 1:B1 2:A0 3:A1
        const int isA  = r >> 1;
        const int half = r & 1;
        const int regByte = (T & 1) * 32768 + (isA ? 0 : 16384) + half * 8192;
        const char* g = (isA ? Ab : Bb) + (size_t)half * (128 * (size_t)K1)
                        + (size_t)T * 64 + offG;
        __builtin_amdgcn_global_load_lds((const AS1 void*)g,
                                         (AS3 void*)(smem + regByte + ldsW),
                                         16, 0, 0);
    };

    // ---- prologue: scale staging, then tile0 + tile1(B0,B1) ----
    // xs: chunk c = (w*7+i)*64 + lane -> kb = w*7+i, 4 rows per lane
#pragma unroll
    for (int i = 0; i < 7; ++i) {
        const int kb = w * 7 + i;
        const float* g = xsT + (size_t)kb * Mdim + bm + lane * 4;
        __builtin_amdgcn_global_load_lds((const AS1 void*)g,
            (AS3 void*)(smem + XS_OFF + kb * 1024), 16, 0, 0);
    }
    if (w == 0 && lane < 28) {
        const float* g = Wsc + (size_t)(bn >> 7) * KB + lane * 4;
        __builtin_amdgcn_global_load_lds((const AS1 void*)g,
            (AS3 void*)(smem + WS_OFF), 16, 0, 0);
    }
    for (int j = 0; j < 6; ++j) stage(j);
    asm volatile("s_waitcnt vmcnt(2)" ::: "memory");  // scales + tile0 resident
    BARRIER();

    f32x4 acc[8][4] = {};

    for (int t = 0; t < NT; ++t) {
        const int buf = t & 1;
        const int kb  = t >> 1;
        const char* aB = smem + buf * 32768 + wr * 8192;
        const char* bB = smem + buf * 32768 + 16384 + (wc >> 1) * 8192;
        ll2 a0[4], a1[4], b0[2], b1[2];
        f32x4 sv[4];

        const float wsv  = *(const float*)(wsL + kb * 4);
        const char* xsLk = xsL0 + (kb << 10);

        // ================= W1 : Q0 + Q1 =================
        stage(4 * t + 6);
#pragma unroll
        for (int m = 0; m < 4; ++m)
            a0[m] = *(const ll2*)(aB + (m * 16 + lr) * 64 + colF);
#pragma unroll
        for (int n = 0; n < 2; ++n)
            b0[n] = *(const ll2*)(bB + (bRow + n * 16 + lr) * 64 + colF);
#pragma unroll
        for (int m = 0; m < 4; ++m)
            sv[m] = *reinterpret_cast<const f32x4*>(xsLk + m * 64) * wsv;
        __builtin_amdgcn_s_setprio(1);
#pragma unroll
        for (int m = 0; m < 4; ++m)
#pragma unroll
            for (int n = 0; n < 2; ++n) {
                f32x4 pacc = {0.f, 0.f, 0.f, 0.f};
                pacc = MFMA_FP8(a0[m][0], b0[n][0], pacc, 0, 0, 0);
                pacc = MFMA_FP8(a0[m][1], b0[n][1], pacc, 0, 0, 0);
                acc[m][n] += sv[m] * pacc;
            }
        __builtin_amdgcn_s_setprio(0);

        stage(4 * t + 7);
#pragma unroll
        for (int n = 0; n < 2; ++n)
            b1[n] = *(const ll2*)(bB + (bRow + (n + 2) * 16 + lr) * 64 + colF);
        __builtin_amdgcn_s_setprio(1);
#pragma unroll
        for (int m = 0; m < 4; ++m)
#pragma unroll
            for (int n = 0; n < 2; ++n) {
                f32x4 pacc = {0.f, 0.f, 0.f, 0.f};
                pacc = MFMA_FP8(a0[m][0], b1[n][0], pacc, 0, 0, 0);
                pacc = MFMA_FP8(a0[m][1], b1[n][1], pacc, 0, 0, 0);
                acc[m][n + 2] += sv[m] * pacc;
            }
        __builtin_amdgcn_s_setprio(0);
        BARRIER();   // W1 -> W2

        // ================= W2 : Q2 + Q3 =================
        stage(4 * t + 8);
#pragma unroll
        for (int m = 0; m < 4; ++m)
            a1[m] = *(const ll2*)(aB + ((m + 4) * 16 + lr) * 64 + colF);
#pragma unroll
        for (int m = 0; m < 4; ++m)
            sv[m] = *reinterpret_cast<const f32x4*>(xsLk + 256 + m * 64) * wsv;
        __builtin_amdgcn_s_setprio(1);
#pragma unroll
        for (int m = 0; m < 4; ++m)
#pragma unroll
            for (int n = 0; n < 2; ++n) {
                f32x4 pacc = {0.f, 0.f, 0.f, 0.f};
                pacc = MFMA_FP8(a1[m][0], b0[n][0], pacc, 0, 0, 0);
                pacc = MFMA_FP8(a1[m][1], b0[n][1], pacc, 0, 0, 0);
                acc[m + 4][n] += sv[m] * pacc;
            }
        __builtin_amdgcn_s_setprio(0);

        stage(4 * t + 9);
        __builtin_amdgcn_s_setprio(1);
#pragma unroll
        for (int m = 0; m < 4; ++m)
#pragma unroll
            for (int n = 0; n < 2; ++n) {
                f32x4 pacc = {0.f, 0.f, 0.f, 0.f};
                pacc = MFMA_FP8(a1[m][0], b1[n][0], pacc, 0, 0, 0);
                pacc = MFMA_FP8(a1[m][1], b1[n][1], pacc, 0, 0, 0);
                acc[m + 4][n + 2] += sv[m] * pacc;
            }
        __builtin_amdgcn_s_setprio(0);
        if (t < NT - 2) { asm volatile("s_waitcnt vmcnt(2)" ::: "memory"); }
        else            { asm volatile("s_waitcnt vmcnt(0)" ::: "memory"); }
        BARRIER();   // tile boundary: tile t+1 fully resident
    }

    // ---- epilogue: C/D layout col = lr, row = lk*4 + j ----
#pragma unroll
    for (int m = 0; m < 8; ++m) {
#pragma unroll
        for (int n = 0; n < 4; ++n) {
            const int row0 = bm + wr * 128 + m * 16 + lk * 4;
            const int col  = bn + wc * 64 + n * 16 + lr;
#pragma unroll
            for (int j = 0; j < 4; ++j)
                C[(size_t)(row0 + j) * Ndim + col] = acc[m][n][j];
        }
    }
}

// ---------------------------------------------------------------------------
extern "C" void kernel_launch(void* const* d_in, const int* in_sizes, int n_in,
                              void* d_out, int out_size, void* d_ws, size_t ws_size,
                              hipStream_t stream) {
    const float* x  = (const float*)d_in[0];
    const float* w  = (const float*)d_in[1];
    const float* ws = (const float*)d_in[2];

    unsigned char* xq  = (unsigned char*)d_ws;                       // 29.4 MB
    unsigned char* w8  = xq + (size_t)Mdim * Kdim;                   // 117.4 MB
    float*         xst = (float*)(w8 + (size_t)Ndim * Kdim);         // 0.92 MB

    quant_x_kernel<<<2048, 256, 0, stream>>>(x, xq, xst);
    quant_w_kernel<<<4096, 256, 0, stream>>>(w, w8);

    hipFuncSetAttribute((const void*)gemm256_fp8_kernel,
                        hipFuncAttributeMaxDynamicSharedMemorySize, LDS_TOT);
    gemm256_fp8_kernel<<<NWG, 512, LDS_TOT, stream>>>(xq, w8, xst, ws,
                                                      (float*)d_out);
}